// Round 6
// baseline (130.541 us; speedup 1.0000x reference)
//
#include <hip/hip_runtime.h>

// LBP for semantic dependency parsing — label-difference form, all 3
// iterations fused, E-only register state (D recomputed from q-history).
//
//   E[b,i,j,k]  = 2^(log2e*s[b,i,j,k]) - 1          (only use of the scores)
//   D_0 = 0;  D_t = log2(1+p+E) - log2(1+p),  p = 2^(D_{t-1} - q_{t-1}[i])
//   q_t[k] = q0[k] + mask[k] * sum_i D^sum_t[i,k] * mask[i]*(i!=j)*(i!=k)
//   out[b,k,j] = 1/(1+2^(-q_3[k]))
// Block (b,j) closes the whole recursion for column j. Scores are read from
// HBM exactly once and cached as E in registers. D is NOT stored: pass t
// recomputes D_1..D_{t-1} from q0/q1/q2 (LDS) — +2 log2/score total, in
// exchange for halving register state (round-5 counters showed the 192-reg
// E+D payload forced AGPR round-trips: VGPR=112, VALUBusy 35%, 22% occ).
// Geometry: 1024 thr/block, 4 rows x 4 k per thread -> 48-reg payload,
// <=128 VGPR, 16 waves/CU.

#define TS 128
#define RPT 4           // rows per thread: 32 row-groups x 32 k-quads = 1024 thr

typedef float f4v __attribute__((ext_vector_type(4)));

constexpr float LOG2E = 1.4426950408889634f;

// ---- mask format probe: f[0]!=0 -> byte mask, f[1]!=0 -> float32, else int32
__global__ void flags_init(int* __restrict__ f) { f[0] = 0; f[1] = 0; }

__global__ void mask_detect(const unsigned char* __restrict__ m, int n, int* __restrict__ f) {
    int v1 = 0, v23 = 0;
    for (int i = blockIdx.x * blockDim.x + threadIdx.x; i < n; i += gridDim.x * blockDim.x) {
        const unsigned char b = m[i];           // first n bytes: in-bounds for all layouts
        const int r = i & 3;
        if (r == 1) v1 |= b;
        if (r >= 2) v23 |= b;
    }
    const int lane = threadIdx.x & 63;
    if (__any(v1)  && lane == 0) atomicOr(&f[0], 1);
    if (__any(v23) && lane == 0) atomicOr(&f[1], 1);
}

__device__ __forceinline__ float d_first(float E, float p1, float l1) {
    return __log2f(1.0f + p1 + E) - l1;
}
__device__ __forceinline__ float d_next(float Dprev, float q, float E) {
    const float p = exp2f(fminf(Dprev - q, 126.0f));
    const float a = 1.0f + p;
    return __log2f(a + E) - __log2f(a);
}

__global__ __launch_bounds__(1024)
void lbp_fused(const float* __restrict__ s_edge,
               const f4v* __restrict__ sib4,
               const f4v* __restrict__ cop4,
               const f4v* __restrict__ grd4,
               const void* __restrict__ mask,
               const int* __restrict__ flags,
               float* __restrict__ outp)
{
    __shared__ float q0s[TS], p1s[TS], lp1s[TS], q1s[TS], q2s[TS];
    __shared__ f4v red4[32 * 32];       // [row-group][k-quad]
    __shared__ unsigned char mrow[TS];

    const int bj = blockIdx.x;
    const int b  = bj >> 7;
    const int j  = bj & (TS - 1);
    const int t  = threadIdx.x;
    const int kq = t & 31;              // k = 4*kq .. 4*kq+3
    const int rq = t >> 5;              // row group 0..31 (RPT rows each)
    const int i0 = rq * RPT;
    const int k0 = kq * 4;

    // ---- per-column prologue ----
    if (t < TS) {
        const int i = t;
        const int idx = (b * TS + i) * TS + j;
        const float q0 = LOG2E * s_edge[idx];
        q0s[i] = q0;
        const int f1 = flags[0], f23 = flags[1];
        unsigned char mv;
        if (f1)       mv = ((const unsigned char*)mask)[idx] != 0;
        else if (f23) mv = ((const float*)mask)[idx] != 0.0f;
        else          mv = ((const int*)mask)[idx]   != 0;
        mrow[i] = mv;
        const float p1 = exp2f(-q0);
        p1s[i]  = p1;
        lp1s[i] = __log2f(1.0f + p1);
    }
    __syncthreads();

    const size_t colBase4 = (size_t)b * (TS * TS * TS / 4) + (size_t)j * (TS / 4) + kq;

    // ---- pass 1 fused with staging: scores -> E regs, D1 -> acc ----
    f4v Es[RPT], Ec[RPT], Eg[RPT];
    f4v acc;
    acc[0] = acc[1] = acc[2] = acc[3] = 0.0f;
    #pragma unroll
    for (int r = 0; r < RPT; ++r) {
        const int i = i0 + r;
        const size_t off = colBase4 + (size_t)i * (TS * TS / 4);
        const f4v vs = sib4[off];
        const f4v vc = cop4[off];
        const f4v vg = grd4[off];
        const bool live = (mrow[i] != 0) && (i != j);
        const float p1 = p1s[i], l1 = lp1s[i];
        #pragma unroll
        for (int c = 0; c < 4; ++c) {
            const float es = exp2f(LOG2E * vs[c]) - 1.0f;
            const float ec = exp2f(LOG2E * vc[c]) - 1.0f;
            const float eg = exp2f(LOG2E * vg[c]) - 1.0f;
            Es[r][c] = es; Ec[r][c] = ec; Eg[r][c] = eg;
            const float d = d_first(es, p1, l1) + d_first(ec, p1, l1) + d_first(eg, p1, l1);
            if (live && (i != k0 + c)) acc[c] += d;
        }
    }
    red4[t] = acc;
    __syncthreads();
    if (t < TS) {
        const float* red = (const float*)red4;
        float tot = 0.0f;
        #pragma unroll
        for (int g = 0; g < 32; ++g) tot += red[g * TS + t];
        q1s[t] = q0s[t] + (mrow[t] ? tot : 0.0f);
    }
    __syncthreads();

    // ---- pass 2: recompute D1 from q0, update with q1 ----
    acc[0] = acc[1] = acc[2] = acc[3] = 0.0f;
    #pragma unroll
    for (int r = 0; r < RPT; ++r) {
        const int i = i0 + r;
        const bool live = (mrow[i] != 0) && (i != j);
        if (live) {
            const float p1 = p1s[i], l1 = lp1s[i], q1 = q1s[i];
            #pragma unroll
            for (int c = 0; c < 4; ++c) {
                const float es = Es[r][c], ec = Ec[r][c], eg = Eg[r][c];
                const float d2s = d_next(d_first(es, p1, l1), q1, es);
                const float d2c = d_next(d_first(ec, p1, l1), q1, ec);
                const float d2g = d_next(d_first(eg, p1, l1), q1, eg);
                if (i != k0 + c) acc[c] += d2s + d2c + d2g;
            }
        }
    }
    red4[t] = acc;
    __syncthreads();
    if (t < TS) {
        const float* red = (const float*)red4;
        float tot = 0.0f;
        #pragma unroll
        for (int g = 0; g < 32; ++g) tot += red[g * TS + t];
        q2s[t] = q0s[t] + (mrow[t] ? tot : 0.0f);
    }
    __syncthreads();

    // ---- pass 3: recompute D1,D2 from q0,q1, update with q2 ----
    acc[0] = acc[1] = acc[2] = acc[3] = 0.0f;
    #pragma unroll
    for (int r = 0; r < RPT; ++r) {
        const int i = i0 + r;
        const bool live = (mrow[i] != 0) && (i != j);
        if (live) {
            const float p1 = p1s[i], l1 = lp1s[i], q1 = q1s[i], q2 = q2s[i];
            #pragma unroll
            for (int c = 0; c < 4; ++c) {
                const float es = Es[r][c], ec = Ec[r][c], eg = Eg[r][c];
                const float d3s = d_next(d_next(d_first(es, p1, l1), q1, es), q2, es);
                const float d3c = d_next(d_next(d_first(ec, p1, l1), q1, ec), q2, ec);
                const float d3g = d_next(d_next(d_first(eg, p1, l1), q1, eg), q2, eg);
                if (i != k0 + c) acc[c] += d3s + d3c + d3g;
            }
        }
    }
    red4[t] = acc;
    __syncthreads();
    if (t < TS) {
        const float* red = (const float*)red4;
        float tot = 0.0f;
        #pragma unroll
        for (int g = 0; g < 32; ++g) tot += red[g * TS + t];
        const float q3 = q0s[t] + (mrow[t] ? tot : 0.0f);
        outp[(b * TS + t) * TS + j] = 1.0f / (1.0f + exp2f(-q3));
    }
}

extern "C" void kernel_launch(void* const* d_in, const int* in_sizes, int n_in,
                              void* d_out, int out_size, void* d_ws, size_t ws_size,
                              hipStream_t stream) {
    const float* s_edge = (const float*)d_in[0];
    const f4v*   sib4   = (const f4v*)d_in[1];
    const f4v*   cop4   = (const f4v*)d_in[2];
    const f4v*   grd4   = (const f4v*)d_in[3];
    const void*  mask   = d_in[4];
    float* out = (float*)d_out;

    const int Bn = in_sizes[0] / (TS * TS);   // batch
    const int nMask = in_sizes[4];            // B*S*S elements

    int* flags = (int*)d_ws;

    flags_init<<<1, 1, 0, stream>>>(flags);
    mask_detect<<<64, 256, 0, stream>>>((const unsigned char*)mask, nMask, flags);
    lbp_fused<<<Bn * TS, 1024, 0, stream>>>(s_edge, sib4, cop4, grd4, mask, flags, out);
}

// Round 7
// 129.293 us; speedup vs baseline: 1.0097x; 1.0097x over previous
//
#include <hip/hip_runtime.h>

// LBP for semantic dependency parsing — label-difference form, all 3
// iterations fused, F-only fp16 register state (D recomputed from q-history).
//
//   F[b,i,j,k] = 2^(log2e*s[b,i,j,k]) = e^s      (only use of the scores)
//   D_0 = 0;  D_t = log2(p + F) - log2(1 + p),   p = 2^(D_{t-1} - q_{t-1}[i])
//   (pass 1: p1 = 2^(-q0) shared per row, l1 = log2(1+p1))
//   q_t[k] = q0[k] + mask[k] * sum_i D^sum_t[i,k] * mask[i]*(i!=j)*(i!=k)
//   out[b,k,j] = 1/(1+2^(-q_3[k]))
//
// Block (b,j) closes the whole recursion for column j; scores are read from
// HBM exactly once and cached as F in PACKED FP16 registers (uniform relative
// error 2^-11 -> <1e-3 output error; storing E=F-1 would lose precision near
// E~-1). Payload = 3 arrays x 8 rows x half4 = 48 VGPRs, sized to fit the
// compiler's preferred 4-waves/SIMD point WITH temps (rounds 4-6 showed the
// allocator sheds oversized payloads to AGPR moves / scratch spills instead
// of using a bigger register budget).

#define TS 128
#define RPT 8           // rows per thread: 16 row-groups x 32 k-quads = 512 thr

typedef float f4v __attribute__((ext_vector_type(4)));
typedef _Float16 h4v __attribute__((ext_vector_type(4)));

constexpr float LOG2E = 1.4426950408889634f;

// ---- mask format probe: f[0]!=0 -> byte mask, f[1]!=0 -> float32, else int32
__global__ void flags_init(int* __restrict__ f) { f[0] = 0; f[1] = 0; }

__global__ void mask_detect(const unsigned char* __restrict__ m, int n, int* __restrict__ f) {
    int v1 = 0, v23 = 0;
    for (int i = blockIdx.x * blockDim.x + threadIdx.x; i < n; i += gridDim.x * blockDim.x) {
        const unsigned char b = m[i];           // first n bytes: in-bounds for all layouts
        const int r = i & 3;
        if (r == 1) v1 |= b;
        if (r >= 2) v23 |= b;
    }
    const int lane = threadIdx.x & 63;
    if (__any(v1)  && lane == 0) atomicOr(&f[0], 1);
    if (__any(v23) && lane == 0) atomicOr(&f[1], 1);
}

__device__ __forceinline__ float d_first(float F, float p1, float l1) {
    return __log2f(p1 + F) - l1;
}
__device__ __forceinline__ float d_next(float Dprev, float q, float F) {
    const float p = exp2f(fminf(Dprev - q, 126.0f));
    return __log2f(p + F) - __log2f(1.0f + p);
}

__global__ __launch_bounds__(512, 4)
void lbp_fused(const float* __restrict__ s_edge,
               const f4v* __restrict__ sib4,
               const f4v* __restrict__ cop4,
               const f4v* __restrict__ grd4,
               const void* __restrict__ mask,
               const int* __restrict__ flags,
               float* __restrict__ outp)
{
    __shared__ float q0s[TS], p1s[TS], lp1s[TS], q1s[TS], q2s[TS];
    __shared__ f4v red4[16 * 32];       // [row-group][k-quad]
    __shared__ unsigned char mrow[TS];

    const int bj = blockIdx.x;
    const int b  = bj >> 7;
    const int j  = bj & (TS - 1);
    const int t  = threadIdx.x;
    const int kq = t & 31;              // k = 4*kq .. 4*kq+3
    const int rq = t >> 5;              // row group 0..15 (RPT rows each)
    const int i0 = rq * RPT;
    const int k0 = kq * 4;

    // ---- per-column prologue ----
    if (t < TS) {
        const int i = t;
        const int idx = (b * TS + i) * TS + j;
        const float q0 = LOG2E * s_edge[idx];
        q0s[i] = q0;
        const int f1 = flags[0], f23 = flags[1];
        unsigned char mv;
        if (f1)       mv = ((const unsigned char*)mask)[idx] != 0;
        else if (f23) mv = ((const float*)mask)[idx] != 0.0f;
        else          mv = ((const int*)mask)[idx]   != 0;
        mrow[i] = mv;
        const float p1 = exp2f(-q0);
        p1s[i]  = p1;
        lp1s[i] = __log2f(1.0f + p1);
    }
    __syncthreads();

    const size_t colBase4 = (size_t)b * (TS * TS * TS / 4) + (size_t)j * (TS / 4) + kq;

    // ---- pass 1 fused with staging: scores -> F (packed fp16), D1 -> acc ----
    h4v Fs[RPT], Fc[RPT], Fg[RPT];
    f4v acc;
    acc[0] = acc[1] = acc[2] = acc[3] = 0.0f;
    #pragma unroll
    for (int r = 0; r < RPT; ++r) {
        const int i = i0 + r;
        const size_t off = colBase4 + (size_t)i * (TS * TS / 4);
        const f4v vs = sib4[off];
        const f4v vc = cop4[off];
        const f4v vg = grd4[off];
        f4v fs, fc, fg;
        #pragma unroll
        for (int c = 0; c < 4; ++c) {
            fs[c] = exp2f(LOG2E * vs[c]);
            fc[c] = exp2f(LOG2E * vc[c]);
            fg[c] = exp2f(LOG2E * vg[c]);
        }
        Fs[r] = __builtin_convertvector(fs, h4v);
        Fc[r] = __builtin_convertvector(fc, h4v);
        Fg[r] = __builtin_convertvector(fg, h4v);
        const bool live = (mrow[i] != 0) && (i != j);
        const float p1 = p1s[i], l1 = lp1s[i];
        #pragma unroll
        for (int c = 0; c < 4; ++c) {
            const float d = d_first(fs[c], p1, l1) + d_first(fc[c], p1, l1)
                          + d_first(fg[c], p1, l1);
            if (live && (i != k0 + c)) acc[c] += d;
        }
    }
    red4[t] = acc;
    __syncthreads();
    if (t < TS) {
        const float* red = (const float*)red4;
        float tot = 0.0f;
        #pragma unroll
        for (int g = 0; g < 16; ++g) tot += red[g * TS + t];
        q1s[t] = q0s[t] + (mrow[t] ? tot : 0.0f);
    }
    __syncthreads();

    // ---- pass 2: recompute D1 from q0, update with q1 ----
    acc[0] = acc[1] = acc[2] = acc[3] = 0.0f;
    #pragma unroll
    for (int r = 0; r < RPT; ++r) {
        const int i = i0 + r;
        const bool live = (mrow[i] != 0) && (i != j);
        if (live) {
            const float p1 = p1s[i], l1 = lp1s[i], q1 = q1s[i];
            const f4v fs = __builtin_convertvector(Fs[r], f4v);
            const f4v fc = __builtin_convertvector(Fc[r], f4v);
            const f4v fg = __builtin_convertvector(Fg[r], f4v);
            #pragma unroll
            for (int c = 0; c < 4; ++c) {
                const float d2s = d_next(d_first(fs[c], p1, l1), q1, fs[c]);
                const float d2c = d_next(d_first(fc[c], p1, l1), q1, fc[c]);
                const float d2g = d_next(d_first(fg[c], p1, l1), q1, fg[c]);
                if (i != k0 + c) acc[c] += d2s + d2c + d2g;
            }
        }
    }
    red4[t] = acc;
    __syncthreads();
    if (t < TS) {
        const float* red = (const float*)red4;
        float tot = 0.0f;
        #pragma unroll
        for (int g = 0; g < 16; ++g) tot += red[g * TS + t];
        q2s[t] = q0s[t] + (mrow[t] ? tot : 0.0f);
    }
    __syncthreads();

    // ---- pass 3: recompute D1,D2 from q0,q1, update with q2 ----
    acc[0] = acc[1] = acc[2] = acc[3] = 0.0f;
    #pragma unroll
    for (int r = 0; r < RPT; ++r) {
        const int i = i0 + r;
        const bool live = (mrow[i] != 0) && (i != j);
        if (live) {
            const float p1 = p1s[i], l1 = lp1s[i], q1 = q1s[i], q2 = q2s[i];
            const f4v fs = __builtin_convertvector(Fs[r], f4v);
            const f4v fc = __builtin_convertvector(Fc[r], f4v);
            const f4v fg = __builtin_convertvector(Fg[r], f4v);
            #pragma unroll
            for (int c = 0; c < 4; ++c) {
                const float d3s = d_next(d_next(d_first(fs[c], p1, l1), q1, fs[c]), q2, fs[c]);
                const float d3c = d_next(d_next(d_first(fc[c], p1, l1), q1, fc[c]), q2, fc[c]);
                const float d3g = d_next(d_next(d_first(fg[c], p1, l1), q1, fg[c]), q2, fg[c]);
                if (i != k0 + c) acc[c] += d3s + d3c + d3g;
            }
        }
    }
    red4[t] = acc;
    __syncthreads();
    if (t < TS) {
        const float* red = (const float*)red4;
        float tot = 0.0f;
        #pragma unroll
        for (int g = 0; g < 16; ++g) tot += red[g * TS + t];
        const float q3 = q0s[t] + (mrow[t] ? tot : 0.0f);
        outp[(b * TS + t) * TS + j] = 1.0f / (1.0f + exp2f(-q3));
    }
}

extern "C" void kernel_launch(void* const* d_in, const int* in_sizes, int n_in,
                              void* d_out, int out_size, void* d_ws, size_t ws_size,
                              hipStream_t stream) {
    const float* s_edge = (const float*)d_in[0];
    const f4v*   sib4   = (const f4v*)d_in[1];
    const f4v*   cop4   = (const f4v*)d_in[2];
    const f4v*   grd4   = (const f4v*)d_in[3];
    const void*  mask   = d_in[4];
    float* out = (float*)d_out;

    const int Bn = in_sizes[0] / (TS * TS);   // batch
    const int nMask = in_sizes[4];            // B*S*S elements

    int* flags = (int*)d_ws;

    flags_init<<<1, 1, 0, stream>>>(flags);
    mask_detect<<<64, 256, 0, stream>>>((const unsigned char*)mask, nMask, flags);
    lbp_fused<<<Bn * TS, 512, 0, stream>>>(s_edge, sib4, cop4, grd4, mask, flags, out);
}